// Round 10
// baseline (461.956 us; speedup 1.0000x reference)
//
#include <hip/hip_runtime.h>

// WKV7 (RWKV-7) forward scan. T=2048, H=64, D=64.
// R10 = R7's lookahead algebra + R9's asm-controlled reduce placement.
//   sa_{t+1} = R2 + beta*sa_t + gamma*vv_t
//     R2 = sum_j (S_{t-1}∘e_t)[i,j] a_{t+1}[j], beta = b_t·a_{t+1},
//     gamma = k_t·a_{t+1}
//   Body t: partials (pre-update s) -> s update -> ONE asm block with FOUR
//   interleaved 4-level DPP chains (R2, beta, gamma, y_{t-1}) -> y_t partial
//   -> y_{t-1} store -> stage -> compose sa_{t+1} (2 fma).
//   Carried chains: sa = 2 fma/step, s = 3 fma levels/step. The reduce path
//   spans two bodies -> its latency no longer binds.
// Memory machinery identical to R7/R9 (8-slot global_load_lds ring, 3-deep
// reads, vmcnt(30), lgkmcnt(6) tied to consumed regs).

typedef float f32x4 __attribute__((ext_vector_type(4)));

constexpr int T_LEN = 2048;
constexpr int DD    = 64;
constexpr int HD    = 64 * 64;   // 4096

#define AS1 __attribute__((address_space(1)))
#define AS3 __attribute__((address_space(3)))

struct Buf { f32x4 r, e, k, a, b; float vv; };

__global__ __launch_bounds__(256)
void exp_kernel(const float4* __restrict__ w, float4* __restrict__ ew, int n4) {
  int i = blockIdx.x * blockDim.x + threadIdx.x;
  int stride = gridDim.x * blockDim.x;
  for (; i < n4; i += stride) {
    float4 x = w[i];
    float4 o;
    o.x = __expf(x.x); o.y = __expf(x.y); o.z = __expf(x.z); o.w = __expf(x.w);
    ew[i] = o;
  }
}

template<int CTRL>
__device__ __forceinline__ float dpp_add(float x) {
  int y = __builtin_amdgcn_update_dpp(0, __float_as_int(x), CTRL, 0xf, 0xf, true);
  return x + __int_as_float(y);
}

// Serial 16-lane reduce (prologue/epilogue only).
__device__ __forceinline__ float row16_reduce(float x) {
  x = dpp_add<0xB1>(x);    // quad_perm [1,0,3,2]
  x = dpp_add<0x4E>(x);    // quad_perm [2,3,0,1]
  x = dpp_add<0x141>(x);   // row_half_mirror
  x = dpp_add<0x140>(x);   // row_mirror
  return x;
}

// FOUR row-of-16 reductions, levels interleaved. Dependent ops are 4
// instructions apart -> no interior wait-states needed (VALU->DPP hazard
// needs 2). s_nop 1 covers the entry hazard (R8 lesson).
__device__ __forceinline__ void quad_reduce(float& a, float& b, float& c, float& d) {
  float t0, t1, t2, t3;
  asm volatile(
    "s_nop 1\n\t"
    "v_mov_b32_dpp %4, %0 quad_perm:[1,0,3,2] row_mask:0xf bank_mask:0xf\n\t"
    "v_mov_b32_dpp %5, %1 quad_perm:[1,0,3,2] row_mask:0xf bank_mask:0xf\n\t"
    "v_mov_b32_dpp %6, %2 quad_perm:[1,0,3,2] row_mask:0xf bank_mask:0xf\n\t"
    "v_mov_b32_dpp %7, %3 quad_perm:[1,0,3,2] row_mask:0xf bank_mask:0xf\n\t"
    "v_add_f32 %0, %0, %4\n\t"
    "v_add_f32 %1, %1, %5\n\t"
    "v_add_f32 %2, %2, %6\n\t"
    "v_add_f32 %3, %3, %7\n\t"
    "v_mov_b32_dpp %4, %0 quad_perm:[2,3,0,1] row_mask:0xf bank_mask:0xf\n\t"
    "v_mov_b32_dpp %5, %1 quad_perm:[2,3,0,1] row_mask:0xf bank_mask:0xf\n\t"
    "v_mov_b32_dpp %6, %2 quad_perm:[2,3,0,1] row_mask:0xf bank_mask:0xf\n\t"
    "v_mov_b32_dpp %7, %3 quad_perm:[2,3,0,1] row_mask:0xf bank_mask:0xf\n\t"
    "v_add_f32 %0, %0, %4\n\t"
    "v_add_f32 %1, %1, %5\n\t"
    "v_add_f32 %2, %2, %6\n\t"
    "v_add_f32 %3, %3, %7\n\t"
    "v_mov_b32_dpp %4, %0 row_half_mirror row_mask:0xf bank_mask:0xf\n\t"
    "v_mov_b32_dpp %5, %1 row_half_mirror row_mask:0xf bank_mask:0xf\n\t"
    "v_mov_b32_dpp %6, %2 row_half_mirror row_mask:0xf bank_mask:0xf\n\t"
    "v_mov_b32_dpp %7, %3 row_half_mirror row_mask:0xf bank_mask:0xf\n\t"
    "v_add_f32 %0, %0, %4\n\t"
    "v_add_f32 %1, %1, %5\n\t"
    "v_add_f32 %2, %2, %6\n\t"
    "v_add_f32 %3, %3, %7\n\t"
    "v_mov_b32_dpp %4, %0 row_mirror row_mask:0xf bank_mask:0xf\n\t"
    "v_mov_b32_dpp %5, %1 row_mirror row_mask:0xf bank_mask:0xf\n\t"
    "v_mov_b32_dpp %6, %2 row_mirror row_mask:0xf bank_mask:0xf\n\t"
    "v_mov_b32_dpp %7, %3 row_mirror row_mask:0xf bank_mask:0xf\n\t"
    "v_add_f32 %0, %0, %4\n\t"
    "v_add_f32 %1, %1, %5\n\t"
    "v_add_f32 %2, %2, %6\n\t"
    "v_add_f32 %3, %3, %7"
    : "+v"(a), "+v"(b), "+v"(c), "+v"(d),
      "=&v"(t0), "=&v"(t1), "=&v"(t2), "=&v"(t3));
}

__device__ __forceinline__ float dot4(const f32x4& x, const f32x4& y) {
  return fmaf(x[3], y[3], fmaf(x[2], y[2], fmaf(x[1], y[1], x[0] * y[0])));
}

__device__ __forceinline__ void gload_lds(const float* g, const float* l) {
  __builtin_amdgcn_global_load_lds((const AS1 unsigned*)g, (AS3 unsigned*)l, 4, 0, 0);
}

__global__ __launch_bounds__(64, 1)
void wkv7_scan(const float* __restrict__ R, const float* __restrict__ EW,
               const float* __restrict__ K, const float* __restrict__ V,
               const float* __restrict__ A, const float* __restrict__ B,
               const float* __restrict__ S0, float* __restrict__ X,
               float* __restrict__ SOUT)
{
  // 8 slots x (5 vectors + v) x 64 floats = 3072 floats = 12 KB
  __shared__ float smem[3072];

  const int blk = blockIdx.x;          // 0..1023
  const int xcd = blk & 7;
  const int m   = blk >> 3;            // 0..127
  const int h   = xcd * 8 + (m & 7);   // head 0..63
  const int br  = m >> 3;              // row block 0..15

  const int lane = threadIdx.x;        // 0..63
  const int cg   = lane & 15;          // cols [cg*4, cg*4+4)
  const int rl   = lane >> 4;          // local row 0..3
  const int row  = br * 4 + rl;        // 0..63
  const int c0   = cg * 4;

  const int laneoff = h * DD + lane;   // per-lane global offset, all 6 arrays

  const unsigned lb  = (unsigned)(uintptr_t)(AS3 float*)&smem[0];
  const unsigned vab = lb + (unsigned)(cg * 16);   // vector-read base
  const unsigned vvb = lb + (unsigned)(row * 4);   // v-read base (offset:1280)

  const int voffb = (h * DD + row) * 4;   // byte offset of (h,row) in one step

  f32x4 s;
  {
    const f32x4* sp = (const f32x4*)(S0 + (size_t)h * DD * DD + row * DD + c0);
    s = *sp;
  }

  auto stage = [&](int tt, int slot) {
    // uniform step base (SGPR) + per-lane laneoff (VGPR) -> saddr form
    const float* rb = R  + (size_t)tt * HD;
    const float* eb = EW + (size_t)tt * HD;
    const float* kb = K  + (size_t)tt * HD;
    const float* ab = A  + (size_t)tt * HD;
    const float* bb = B  + (size_t)tt * HD;
    const float* vb = V  + (size_t)tt * HD;
    const float* l  = &smem[slot * 384];
    gload_lds(rb + laneoff, l);
    gload_lds(eb + laneoff, l + 64);
    gload_lds(kb + laneoff, l + 128);
    gload_lds(ab + laneoff, l + 192);
    gload_lds(bb + laneoff, l + 256);
    gload_lds(vb + laneoff, l + 320);
  };

  auto lds_read = [&](Buf& d, int slot) {
    unsigned va = vab + (unsigned)(slot * 1536);
    unsigned vv = vvb + (unsigned)(slot * 1536);
    asm volatile(
      "ds_read_b128 %0, %6\n\t"
      "ds_read_b128 %1, %6 offset:256\n\t"
      "ds_read_b128 %2, %6 offset:512\n\t"
      "ds_read_b128 %3, %6 offset:768\n\t"
      "ds_read_b128 %4, %6 offset:1024\n\t"
      "ds_read_b32  %5, %7 offset:1280"
      : "=&v"(d.r), "=&v"(d.e), "=&v"(d.k), "=&v"(d.a), "=&v"(d.b), "=&v"(d.vv)
      : "v"(va), "v"(vv) : "memory");
  };

  auto wait_nx1 = [&](Buf& d) {
    asm volatile("s_waitcnt lgkmcnt(6)"
                 : "+v"(d.r), "+v"(d.e), "+v"(d.k), "+v"(d.a), "+v"(d.b),
                   "+v"(d.vv));
  };

  float sa;             // sa_t, ready at body t entry (composed end of t-1)
  float ypart = 0.0f;   // y_{t-1} partial dot (pre-reduce)
  int   yoff_prev = 2047 * (HD * 4) + voffb;  // body-0 dummy target,
                                              // overwritten by the epilogue

  auto body = [&](Buf& cur, Buf& nx1, Buf& nx2, int t) {
    // stage t+2 resident: >=30 newer vmem ops (5 bodies x (6 loads+1 store)).
    asm volatile("s_waitcnt vmcnt(30)" ::: "memory");
    lds_read(nx2, (t + 2) & 7);
    wait_nx1(nx1);

    // ---- partials for step t+1 (s is PRE-update = S_{t-1}) ----
    f32x4 se;
    se[0] = s[0] * cur.e[0];
    se[1] = s[1] * cur.e[1];
    se[2] = s[2] * cur.e[2];
    se[3] = s[3] * cur.e[3];
    float pR2 = dot4(se, nx1.a);
    float pB  = dot4(cur.b, nx1.a);
    float pG  = dot4(cur.k, nx1.a);
    float pY  = ypart;               // y_{t-1}, computed last body

    // ---- state update for step t (sa ready since last body; se reused) ----
    const float vv = cur.vv;
    s[0] = fmaf(sa, cur.b[0], fmaf(vv, cur.k[0], se[0]));
    s[1] = fmaf(sa, cur.b[1], fmaf(vv, cur.k[1], se[1]));
    s[2] = fmaf(sa, cur.b[2], fmaf(vv, cur.k[2], se[2]));
    s[3] = fmaf(sa, cur.b[3], fmaf(vv, cur.k[3], se[3]));

    // ---- four interleaved reductions (R2, beta, gamma, y_{t-1}) ----
    quad_reduce(pR2, pB, pG, pY);

    // ---- y_t partial (updated s), off the carried chain ----
    ypart = dot4(s, cur.r);

    // ---- store y_{t-1} ----
    if (cg == 0) {
      asm volatile("global_store_dword %0, %1, %2"
                   :: "v"(yoff_prev), "v"(pY), "s"(X) : "memory");
    }
    yoff_prev = t * (HD * 4) + voffb;

    stage((t + 8) & (T_LEN - 1), t & 7);

    // ---- compose sa_{t+1}: 2 fma, the whole carried scalar chain ----
    sa = fmaf(pB, sa, fmaf(pG, vv, pR2));
  };

  // Prologue: fill ring (issue order = count order).
  for (int i = 0; i < 8; ++i) {
    stage(i, i);
    __builtin_amdgcn_sched_barrier(0);
  }
  asm volatile("s_waitcnt vmcnt(36)" ::: "memory");  // stages 0,1 done

  Buf B0, B1, B2, B3;
  lds_read(B0, 0);
  lds_read(B1, 1);
  asm volatile("s_waitcnt lgkmcnt(0)"
               : "+v"(B0.r), "+v"(B0.e), "+v"(B0.k), "+v"(B0.a), "+v"(B0.b),
                 "+v"(B0.vv), "+v"(B1.a));

  // sa_0 = S_init . a_0 (prologue pays one serial reduce)
  sa = row16_reduce(dot4(s, B0.a));

  for (int t = 0; t < T_LEN; t += 4) {
    body(B0, B1, B2, t);
    body(B1, B2, B3, t + 1);
    body(B2, B3, B0, t + 2);
    body(B3, B0, B1, t + 3);
  }

  // Epilogue: reduce+store final y (t=2047); also overwrites body-0 dummy.
  {
    float y = row16_reduce(ypart);
    if (cg == 0) {
      asm volatile("global_store_dword %0, %1, %2"
                   :: "v"(yoff_prev), "v"(y), "s"(X) : "memory");
    }
  }

  *(f32x4*)(SOUT + (size_t)h * DD * DD + row * DD + c0) = s;
}

extern "C" void kernel_launch(void* const* d_in, const int* in_sizes, int n_in,
                              void* d_out, int out_size, void* d_ws, size_t ws_size,
                              hipStream_t stream) {
  // setup_inputs order: seq_length, r, w, k, v, a, b, state2
  const float* r  = (const float*)d_in[1];
  const float* w  = (const float*)d_in[2];
  const float* k  = (const float*)d_in[3];
  const float* v  = (const float*)d_in[4];
  const float* a  = (const float*)d_in[5];
  const float* b  = (const float*)d_in[6];
  const float* s0 = (const float*)d_in[7];

  float* x    = (float*)d_out;                     // (T, H, 1, D)
  float* sout = x + (size_t)T_LEN * HD;            // (H, D, D)

  float* ew = (float*)d_ws;
  (void)ws_size; (void)in_sizes; (void)n_in;

  int n4 = T_LEN * HD / 4;
  hipLaunchKernelGGL(exp_kernel, dim3(1024), dim3(256), 0, stream,
                     (const float4*)w, (float4*)ew, n4);
  hipLaunchKernelGGL(wkv7_scan, dim3(1024), dim3(64), 0, stream,
                     r, ew, k, v, a, b, s0, x, sout);
}

// Round 11
// 356.360 us; speedup vs baseline: 1.2963x; 1.2963x over previous
//
#include <hip/hip_runtime.h>

// WKV7 (RWKV-7) forward scan. T=2048, H=64, D=64.
// R11: staging machinery ablation — LDS ring REMOVED. Inputs load straight
// to registers via pinned asm global_load_dwordx4 (compiler can't sink),
// 4 named buffers, prefetch distance 3, counted vmcnt waits:
//   vmcnt(21) guards cur  (3 newer bodies x (6 loads + 1 store))
//   vmcnt(15) guards nx1.a (t-2's store + t-1's 7 + t's 7, before dots)
// Body algebra = R9 (best so far): direct sa recurrence, dual interleaved
// DPP reduce (s_nop 1 entry hazard guard), y-store pipelined one body.
// Theory being tested: the invariant ~250 cyc/step stall of R5-R10 is the
// global_load_lds->LDS->ds_read machinery, not VALU or chain latency.

typedef float f32x4 __attribute__((ext_vector_type(4)));

constexpr int T_LEN = 2048;
constexpr int DD    = 64;
constexpr int HD    = 64 * 64;   // 4096

struct Buf { f32x4 r, e, k, a, b; float vv; };

__global__ __launch_bounds__(256)
void exp_kernel(const float4* __restrict__ w, float4* __restrict__ ew, int n4) {
  int i = blockIdx.x * blockDim.x + threadIdx.x;
  int stride = gridDim.x * blockDim.x;
  for (; i < n4; i += stride) {
    float4 x = w[i];
    float4 o;
    o.x = __expf(x.x); o.y = __expf(x.y); o.z = __expf(x.z); o.w = __expf(x.w);
    ew[i] = o;
  }
}

template<int CTRL>
__device__ __forceinline__ float dpp_add(float x) {
  int y = __builtin_amdgcn_update_dpp(0, __float_as_int(x), CTRL, 0xf, 0xf, true);
  return x + __int_as_float(y);
}

// Serial 16-lane reduce (prologue/epilogue only).
__device__ __forceinline__ float row16_reduce(float x) {
  x = dpp_add<0xB1>(x);    // quad_perm [1,0,3,2]
  x = dpp_add<0x4E>(x);    // quad_perm [2,3,0,1]
  x = dpp_add<0x141>(x);   // row_half_mirror
  x = dpp_add<0x140>(x);   // row_mirror
  return x;
}

// Two interleaved row-of-16 reductions; s_nop 1 covers the entry
// VALU-write -> DPP-read hazard (R8 lesson).
__device__ __forceinline__ void duo_reduce(float& a, float& b) {
  float t0, t1;
  asm volatile(
    "s_nop 1\n\t"
    "v_mov_b32_dpp %2, %0 quad_perm:[1,0,3,2] row_mask:0xf bank_mask:0xf\n\t"
    "v_mov_b32_dpp %3, %1 quad_perm:[1,0,3,2] row_mask:0xf bank_mask:0xf\n\t"
    "s_nop 0\n\t"
    "v_add_f32 %0, %0, %2\n\t"
    "v_add_f32 %1, %1, %3\n\t"
    "s_nop 0\n\t"
    "v_mov_b32_dpp %2, %0 quad_perm:[2,3,0,1] row_mask:0xf bank_mask:0xf\n\t"
    "v_mov_b32_dpp %3, %1 quad_perm:[2,3,0,1] row_mask:0xf bank_mask:0xf\n\t"
    "s_nop 0\n\t"
    "v_add_f32 %0, %0, %2\n\t"
    "v_add_f32 %1, %1, %3\n\t"
    "s_nop 0\n\t"
    "v_mov_b32_dpp %2, %0 row_half_mirror row_mask:0xf bank_mask:0xf\n\t"
    "v_mov_b32_dpp %3, %1 row_half_mirror row_mask:0xf bank_mask:0xf\n\t"
    "s_nop 0\n\t"
    "v_add_f32 %0, %0, %2\n\t"
    "v_add_f32 %1, %1, %3\n\t"
    "s_nop 0\n\t"
    "v_mov_b32_dpp %2, %0 row_mirror row_mask:0xf bank_mask:0xf\n\t"
    "v_mov_b32_dpp %3, %1 row_mirror row_mask:0xf bank_mask:0xf\n\t"
    "s_nop 0\n\t"
    "v_add_f32 %0, %0, %2\n\t"
    "v_add_f32 %1, %1, %3"
    : "+v"(a), "+v"(b), "=&v"(t0), "=&v"(t1));
}

__device__ __forceinline__ float dot4(const f32x4& x, const f32x4& y) {
  return fmaf(x[3], y[3], fmaf(x[2], y[2], fmaf(x[1], y[1], x[0] * y[0])));
}

__device__ __forceinline__ void gload4(f32x4& d, const float* base, int voffb) {
  asm volatile("global_load_dwordx4 %0, %1, %2"
               : "=v"(d) : "v"(voffb), "s"(base) : "memory");
}
__device__ __forceinline__ void gload1(float& d, const float* base, int voffb) {
  asm volatile("global_load_dword %0, %1, %2"
               : "=v"(d) : "v"(voffb), "s"(base) : "memory");
}

__global__ __launch_bounds__(64, 1)
void wkv7_scan(const float* __restrict__ R, const float* __restrict__ EW,
               const float* __restrict__ K, const float* __restrict__ V,
               const float* __restrict__ A, const float* __restrict__ B,
               const float* __restrict__ S0, float* __restrict__ X,
               float* __restrict__ SOUT)
{
  const int blk = blockIdx.x;          // 0..1023
  // XCD co-location: 8 whole heads (16 row-blocks each) per XCD for L2 reuse.
  const int xcd = blk & 7;
  const int m   = blk >> 3;            // 0..127
  const int h   = xcd * 8 + (m & 7);   // head 0..63
  const int br  = m >> 3;              // row block 0..15

  const int lane = threadIdx.x;        // 0..63
  const int cg   = lane & 15;          // cols [cg*4, cg*4+4)
  const int rl   = lane >> 4;          // local row 0..3
  const int row  = br * 4 + rl;        // 0..63
  const int c0   = cg * 4;

  const int vb  = (h * DD + c0) * 4;   // per-lane byte offset, column vectors
  const int vvb = (h * DD + row) * 4;  // per-lane byte offset, v / x

  f32x4 s;
  {
    const f32x4* sp = (const f32x4*)(S0 + (size_t)h * DD * DD + row * DD + c0);
    s = *sp;
  }

  auto load = [&](Buf& bf, int tt) {
    const int so = tt * (HD * 4);      // uniform (SALU)
    const int vo = so + vb;            // 1 v_add
    const int wo = so + vvb;           // 1 v_add
    gload4(bf.r, R,  vo);
    gload4(bf.e, EW, vo);
    gload4(bf.k, K,  vo);
    gload4(bf.a, A,  vo);
    gload4(bf.b, B,  vo);
    gload1(bf.vv, V, wo);
  };

  float sa;             // sa_t = S_{t-1}.a_t, ready at body t entry
  float yprev = 0.0f;   // y_{t-1}, stored at body t
  int   yst = 2047 * (HD * 4) + vvb;   // body-0 dummy target (epilogue fixes)

  auto body = [&](Buf& cur, Buf& nx1, Buf& nxt3, int t) {
    // 1. issue loads for step t+3 (pinned; cannot be sunk)
    load(nxt3, (t + 3) & (T_LEN - 1));

    // 2. store y_{t-1} (early, off critical path)
    if (cg == 0) {
      asm volatile("global_store_dword %0, %1, %2"
                   :: "v"(yst), "v"(yprev), "s"(X) : "memory");
    }

    // 3. cur guaranteed: 3 bodies x (6 loads + 1 store) = 21 newer ops.
    asm volatile("s_waitcnt vmcnt(21)" ::: "memory");
    __builtin_amdgcn_sched_barrier(0);

    // 4. state update for step t (sa ready since last body)
    const float vv = cur.vv;
    s[0] = fmaf(cur.e[0], s[0], fmaf(sa, cur.b[0], vv * cur.k[0]));
    s[1] = fmaf(cur.e[1], s[1], fmaf(sa, cur.b[1], vv * cur.k[1]));
    s[2] = fmaf(cur.e[2], s[2], fmaf(sa, cur.b[2], vv * cur.k[2]));
    s[3] = fmaf(cur.e[3], s[3], fmaf(sa, cur.b[3], vv * cur.k[3]));

    // 5. nx1 guaranteed: t-2's store + t-1's 7 + t's 7 = 15 newer ops.
    asm volatile("s_waitcnt vmcnt(15)" ::: "memory");
    __builtin_amdgcn_sched_barrier(0);

    // 6. both dots
    float q  = dot4(s, nx1.a);   // -> sa_{t+1}
    float yd = dot4(s, cur.r);   // -> y_t

    // 7. interleaved dual reduction
    duo_reduce(q, yd);
    sa    = q;
    yprev = yd;
    yst   = t * (HD * 4) + vvb;
  };

  Buf B0, B1, B2, B3;
  load(B0, 0);
  load(B1, 1);
  load(B2, 2);
  asm volatile("s_waitcnt vmcnt(12)" ::: "memory");  // B0 done (12 newer)
  __builtin_amdgcn_sched_barrier(0);

  // sa_0 = S_init . a_0 (prologue pays one serial reduce)
  sa = row16_reduce(dot4(s, B0.a));

  for (int t = 0; t < T_LEN; t += 4) {
    body(B0, B1, B3, t);
    body(B1, B2, B0, t + 1);
    body(B2, B3, B1, t + 2);
    body(B3, B0, B2, t + 3);
  }

  // Epilogue: final y (t=2047) — overwrites body-0's dummy store.
  if (cg == 0) {
    asm volatile("global_store_dword %0, %1, %2"
                 :: "v"(yst), "v"(yprev), "s"(X) : "memory");
  }

  *(f32x4*)(SOUT + (size_t)h * DD * DD + row * DD + c0) = s;
}

extern "C" void kernel_launch(void* const* d_in, const int* in_sizes, int n_in,
                              void* d_out, int out_size, void* d_ws, size_t ws_size,
                              hipStream_t stream) {
  // setup_inputs order: seq_length, r, w, k, v, a, b, state2
  const float* r  = (const float*)d_in[1];
  const float* w  = (const float*)d_in[2];
  const float* k  = (const float*)d_in[3];
  const float* v  = (const float*)d_in[4];
  const float* a  = (const float*)d_in[5];
  const float* b  = (const float*)d_in[6];
  const float* s0 = (const float*)d_in[7];

  float* x    = (float*)d_out;                     // (T, H, 1, D)
  float* sout = x + (size_t)T_LEN * HD;            // (H, D, D)

  float* ew = (float*)d_ws;
  (void)ws_size; (void)in_sizes; (void)n_in;

  int n4 = T_LEN * HD / 4;
  hipLaunchKernelGGL(exp_kernel, dim3(1024), dim3(256), 0, stream,
                     (const float4*)w, (float4*)ew, n4);
  hipLaunchKernelGGL(wkv7_scan, dim3(1024), dim3(64), 0, stream,
                     r, ew, k, v, a, b, s0, x, sout);
}